// Round 1
// baseline (537.892 us; speedup 1.0000x reference)
//
#include <hip/hip_runtime.h>

// RichAttentionLayer: B=2048, S=200, D=192, H1=64, H2=32, IN=768.
// One block per batch b. Layer-1 decomposed:
//   x@W1 = k @ M_b + c_b,  M_b[d,h] = W1a[d,h] + W1d[d,h] + q[d]*W1c[d,h]
//   c_b[h] = b1[h] + sum_d q[d]*(W1b[d,h] - W1d[d,h])
// 64-row S-tiles. GEMM1 h-split across waves; GEMM2/layer3/softmax/o-accum
// fully per-wave -> 3 barriers per tile, no wave-serial sections.
//
// R1: LDS diet 46.9K -> 38.8K via lifetime unions (w2t∪h1buf, qbuf∪scores,
// cpart∪opart, mask as uchar) -> __launch_bounds__(256,4) = 4 blocks/CU
// (16/32 waves, grid 2048 = exactly 2 rounds, no tail). pv shuffles moved
// inline into o-accum loop to cut ~15 VGPR of liveness (128-reg budget).

#define B_N 2048
#define S_N 200
#define D_N 192

typedef __bf16 bf16x8 __attribute__((ext_vector_type(8)));
typedef __bf16 bf16x4 __attribute__((ext_vector_type(4)));
typedef float  f32x4  __attribute__((ext_vector_type(4)));

struct __align__(16) Smem {
  unsigned char kbuf[64*400];     // bf16[64][200] (192 used), row stride 400 B
  union {                         // w2t consumed into regs before phase-B
    unsigned char h1buf[64*144];  // barrier; h1buf first written after it.
    unsigned char w2t[32*144];    // bf16 w2t[k2][h] = W2[h][k2]
  };
  union {                         // qbuf dead after phase-B barrier; scores
    float qbuf[192];              // first written tile 0 post-staging-barrier.
    float scores[256];
  };
  float cbuf[64];
  union {                         // cpart dead after cbuf computed (pre tile
    float cpart[4][64];           // 0); opart first written after final tile
    float opart[4][192];          // barrier.
  };
  unsigned char maskbuf[256];
  float wm[4], wl[4];             // per-wave softmax state
  float w3buf[32];
  float b2buf[32];
  float consts[4];                // a1, a2, b3
};

__global__ __launch_bounds__(256, 4) void rich_attn_kernel(
    const float* __restrict__ query, const float* __restrict__ keys,
    const int*   __restrict__ keys_mask, const float* __restrict__ W1,
    const float* __restrict__ b1, const float* __restrict__ a1,
    const float* __restrict__ W2, const float* __restrict__ b2,
    const float* __restrict__ a2, const float* __restrict__ W3,
    const float* __restrict__ b3, float* __restrict__ out)
{
  __shared__ Smem sm;
  const int tid  = threadIdx.x;
  const int b    = blockIdx.x;
  const int wave = tid >> 6;
  const int lane = tid & 63;
  const int quad = (tid >> 4) & 3;
  const int n16  = tid & 15;

  // ---- phase A: preload q, mask, scalars, W2^T(bf16), W3 ----
  if (tid < 192) sm.qbuf[tid] = query[b*D_N + tid];
  sm.maskbuf[tid] = (tid < 200) ? (unsigned char)(keys_mask[b*S_N + tid] != 0) : 0;
  if (tid < 32)  sm.w3buf[tid] = W3[tid];
  else if (tid < 64) sm.b2buf[tid-32] = b2[tid-32];
  if (tid == 64) { sm.consts[0] = a1[0]; sm.consts[1] = a2[0]; sm.consts[2] = b3[0]; }
  for (int i = tid; i < 64*32; i += 256) {
    int hh = i >> 5, kk = i & 31;                 // W2[h][k2] row-major
    *((__bf16*)&sm.w2t[kk*144 + hh*2]) = (__bf16)W2[i];
  }
  __syncthreads();

  // ---- phase B: c_b partials; per-wave fb1 (M_b cols, registers); fw2 ----
  {
    int hh = tid & 63, pp = tid >> 6;
    float acc = 0.f;
    int d0 = pp*48;
    #pragma unroll 4
    for (int d = d0; d < d0+48; ++d)
      acc += sm.qbuf[d] * (W1[(192+d)*64 + hh] - W1[(576+d)*64 + hh]);
    sm.cpart[pp][hh] = acc;
  }
  bf16x8 fb1[6];                                  // B-frag: M_b[k=t*32+quad*8+j][n=h]
  {
    int h = (wave << 4) | n16;
    #pragma unroll
    for (int t = 0; t < 6; ++t) {
      #pragma unroll
      for (int j = 0; j < 8; ++j) {
        int d = t*32 + quad*8 + j;
        float v = W1[d*64 + h] + W1[(576+d)*64 + h] + sm.qbuf[d]*W1[(384+d)*64 + h];
        fb1[t][j] = (__bf16)v;
      }
    }
  }
  bf16x8 fw2[2][2];                               // B-frags for GEMM2, both n-tiles
  #pragma unroll
  for (int nt2 = 0; nt2 < 2; ++nt2)
    #pragma unroll
    for (int t = 0; t < 2; ++t)
      fw2[nt2][t] = *(const bf16x8*)&sm.w2t[(nt2*16 + n16)*144 + (t*32 + quad*8)*2];
  const float w3v0 = sm.w3buf[n16],      w3v1 = sm.w3buf[16 + n16];
  const float bbv0 = sm.b2buf[n16],      bbv1 = sm.b2buf[16 + n16];
  const float a1v = sm.consts[0], a2v = sm.consts[1], b3v = sm.consts[2];
  __syncthreads();
  if (tid < 64)
    sm.cbuf[tid] = b1[tid] + sm.cpart[0][tid] + sm.cpart[1][tid]
                 + sm.cpart[2][tid] + sm.cpart[3][tid];
  // cbuf first read after tile-0 staging barrier below.

  const float* kb = keys + (size_t)b * (S_N * D_N);
  float m_run = -1e30f, l_run = 0.f;
  f32x4 o = {0.f, 0.f, 0.f, 0.f};                 // lanes 0..47 own d = lane*4..+3 (per wave)

  for (int tile = 0; tile < 4; ++tile) {
    const int s0 = tile * 64;
    // ---- stage 64-row keys tile (f32 -> bf16 LDS), zero-fill past S ----
    #pragma unroll
    for (int i = 0; i < 12; ++i) {
      int f = tid + i*256;                        // 0..3071
      int row = f / 48, c4 = f % 48;
      int sg = s0 + row;
      float4 v = make_float4(0.f, 0.f, 0.f, 0.f);
      if (sg < 200) v = ((const float4*)kb)[sg*48 + c4];
      bf16x4 bv; bv[0]=(__bf16)v.x; bv[1]=(__bf16)v.y; bv[2]=(__bf16)v.z; bv[3]=(__bf16)v.w;
      *(bf16x4*)&sm.kbuf[row*400 + c4*8] = bv;
    }
    __syncthreads();

    // ---- GEMM1: h1_pre[64 x 64]; wave owns h-cols [16w,16w+16) ----
    f32x4 acc1[4];
    #pragma unroll
    for (int mt = 0; mt < 4; ++mt) acc1[mt] = (f32x4){0.f,0.f,0.f,0.f};
    #pragma unroll
    for (int mt = 0; mt < 4; ++mt)
      #pragma unroll
      for (int t = 0; t < 6; ++t) {
        bf16x8 fa = *(const bf16x8*)&sm.kbuf[(mt*16 + n16)*400 + (t*32 + quad*8)*2];
        acc1[mt] = __builtin_amdgcn_mfma_f32_16x16x32_bf16(fa, fb1[t], acc1[mt], 0, 0, 0);
      }
    {
      int h = (wave << 4) | n16;
      float cb = sm.cbuf[h];
      #pragma unroll
      for (int mt = 0; mt < 4; ++mt)
        #pragma unroll
        for (int r = 0; r < 4; ++r) {
          int m = mt*16 + quad*4 + r;             // C layout: row=quad*4+r, col=n16
          float v = acc1[mt][r] + cb;
          v = (v >= 0.f) ? v : a1v * v;
          *((__bf16*)&sm.h1buf[m*144 + h*2]) = (__bf16)v;
        }
    }
    __syncthreads();

    // ---- per-wave from here: rows 16*wave .. 16*wave+15 of this tile ----
    // GEMM2: h2_pre[16 x 32]
    bf16x8 fa2[2];
    #pragma unroll
    for (int t = 0; t < 2; ++t)
      fa2[t] = *(const bf16x8*)&sm.h1buf[(wave*16 + n16)*144 + (t*32 + quad*8)*2];
    f32x4 acc2[2];
    acc2[0] = (f32x4){0.f,0.f,0.f,0.f};
    acc2[1] = (f32x4){0.f,0.f,0.f,0.f};
    #pragma unroll
    for (int nt2 = 0; nt2 < 2; ++nt2)
      #pragma unroll
      for (int t = 0; t < 2; ++t)
        acc2[nt2] = __builtin_amdgcn_mfma_f32_16x16x32_bf16(fa2[t], fw2[nt2][t], acc2[nt2], 0, 0, 0);

    // layer 3 in-register: sc[r] for row (quad*4+r), butterfly-reduce over n16
    float sc[4];
    #pragma unroll
    for (int r = 0; r < 4; ++r) {
      float v0 = acc2[0][r] + bbv0; v0 = (v0 >= 0.f) ? v0 : a2v * v0;
      float v1 = acc2[1][r] + bbv1; v1 = (v1 >= 0.f) ? v1 : a2v * v1;
      sc[r] = v0 * w3v0 + v1 * w3v1;
    }
    #pragma unroll
    for (int off = 1; off < 16; off <<= 1)
      #pragma unroll
      for (int r = 0; r < 4; ++r) sc[r] += __shfl_xor(sc[r], off);

    // mask + per-wave online softmax (wave-local, no barrier)
    float p[4];
    float mloc = -1e30f;
    #pragma unroll
    for (int r = 0; r < 4; ++r) {
      int sg = s0 + wave*16 + quad*4 + r;
      sc[r] += b3v;
      bool valid = (sg < 200) && (sm.maskbuf[sg] != 0);
      sc[r] = valid ? sc[r] : -1e30f;
      mloc = fmaxf(mloc, sc[r]);
    }
    if (n16 == 0) {
      #pragma unroll
      for (int r = 0; r < 4; ++r) sm.scores[s0 + wave*16 + quad*4 + r] = sc[r];
    }
    mloc = fmaxf(mloc, __shfl_xor(mloc, 16));
    mloc = fmaxf(mloc, __shfl_xor(mloc, 32));
    float m_new = fmaxf(m_run, mloc);
    float fac = __expf(m_run - m_new);
    float psum = 0.f;
    #pragma unroll
    for (int r = 0; r < 4; ++r) {
      p[r] = (sc[r] > -1e29f) ? __expf(sc[r] - m_new) : 0.f;
      psum += p[r];
    }
    psum += __shfl_xor(psum, 16);
    psum += __shfl_xor(psum, 32);
    l_run = l_run * fac + psum;
    m_run = m_new;

    // o += p * keys over wave's 16 rows; p broadcast inline (short liveness)
    o[0] *= fac; o[1] *= fac; o[2] *= fac; o[3] *= fac;
    #pragma unroll
    for (int s2 = 0; s2 < 16; ++s2) {
      float pvs = __shfl(p[s2 & 3], (s2 >> 2) * 16);   // all lanes active
      if (lane < 48) {
        bf16x4 kv = *(const bf16x4*)&sm.kbuf[(wave*16 + s2)*400 + lane*8];
        o[0] += pvs * (float)kv[0];
        o[1] += pvs * (float)kv[1];
        o[2] += pvs * (float)kv[2];
        o[3] += pvs * (float)kv[3];
      }
    }
    __syncthreads();   // kbuf/h1buf reuse next tile
  }

  // ---- combine 4 per-wave states, finalize ----
  if (lane == 0) { sm.wm[wave] = m_run; sm.wl[wave] = l_run; }
  if (lane < 48) *(f32x4*)&sm.opart[wave][lane*4] = o;
  __syncthreads();
  float mg = fmaxf(fmaxf(sm.wm[0], sm.wm[1]), fmaxf(sm.wm[2], sm.wm[3]));
  float e0 = __expf(sm.wm[0] - mg), e1 = __expf(sm.wm[1] - mg);
  float e2 = __expf(sm.wm[2] - mg), e3 = __expf(sm.wm[3] - mg);
  float lg = sm.wl[0]*e0 + sm.wl[1]*e1 + sm.wl[2]*e2 + sm.wl[3]*e3;
  float invl = (lg > 0.f) ? 1.f / lg : 0.f;
  if (tid < 192) {
    float os = sm.opart[0][tid]*e0 + sm.opart[1][tid]*e1
             + sm.opart[2][tid]*e2 + sm.opart[3][tid]*e3;
    out[(size_t)b * D_N + tid] = os * invl;
  }
  if (tid < 200) {
    float wv = (lg > 0.f) ? __expf(sm.scores[tid] - mg) * invl : 0.f;
    out[(size_t)B_N * D_N + (size_t)b * S_N + tid] = wv;
  }
}

extern "C" void kernel_launch(void* const* d_in, const int* in_sizes, int n_in,
                              void* d_out, int out_size, void* d_ws, size_t ws_size,
                              hipStream_t stream) {
  const float* query     = (const float*)d_in[0];
  const float* keys      = (const float*)d_in[1];
  const int*   keys_mask = (const int*)  d_in[2];
  const float* W1        = (const float*)d_in[3];
  const float* b1        = (const float*)d_in[4];
  const float* a1        = (const float*)d_in[5];
  const float* W2        = (const float*)d_in[6];
  const float* b2        = (const float*)d_in[7];
  const float* a2        = (const float*)d_in[8];
  const float* W3        = (const float*)d_in[9];
  const float* b3        = (const float*)d_in[10];
  float* out = (float*)d_out;
  rich_attn_kernel<<<dim3(B_N), dim3(256), 0, stream>>>(
      query, keys, keys_mask, W1, b1, a1, W2, b2, a2, W3, b3, out);
}

// Round 3
// 536.279 us; speedup vs baseline: 1.0030x; 1.0030x over previous
//
#include <hip/hip_runtime.h>

// RichAttentionLayer: B=2048, S=200, D=192, H1=64, H2=32, IN=768.
// One block per batch b. Layer-1 decomposed:
//   x@W1 = k @ M_b + c_b,  M_b[d,h] = W1a[d,h] + W1d[d,h] + q[d]*W1c[d,h]
//   c_b[h] = b1[h] + sum_d q[d]*(W1b[d,h] - W1d[d,h])
// 64-row S-tiles. GEMM1 h-split across waves; GEMM2/layer3/softmax/o-accum
// fully per-wave -> 3 barriers per tile, no wave-serial sections.
//
// R1: LDS diet 46.9K -> 38.8K (unions) -> __launch_bounds__(256,4).
// R2: anti-spill scheduling (staging chunked 3x4 + sched_barrier; fb1
//     per-t-group sched_barrier). BUG: rfl() applied to w3v0/w3v1/bbv0/bbv1
//     which are n16-indexed (PER-LANE, not uniform) -> wrong results.
// R3: rfl only on true scalars (a1,a2,b3); per-lane w3/b2 stay in VGPRs.

#define B_N 2048
#define S_N 200
#define D_N 192

typedef __bf16 bf16x8 __attribute__((ext_vector_type(8)));
typedef __bf16 bf16x4 __attribute__((ext_vector_type(4)));
typedef float  f32x4  __attribute__((ext_vector_type(4)));

__device__ __forceinline__ float rfl(float x) {
  return __uint_as_float(__builtin_amdgcn_readfirstlane(__float_as_uint(x)));
}

struct __align__(16) Smem {
  unsigned char kbuf[64*400];     // bf16[64][200] (192 used), row stride 400 B
  union {                         // w2t consumed into regs before phase-B
    unsigned char h1buf[64*144];  // barrier; h1buf first written after it.
    unsigned char w2t[32*144];    // bf16 w2t[k2][h] = W2[h][k2]
  };
  union {                         // qbuf dead after phase-B barrier; scores
    float qbuf[192];              // first written tile 0 post-staging-barrier.
    float scores[256];
  };
  float cbuf[64];
  union {                         // cpart dead after cbuf computed (pre tile
    float cpart[4][64];           // 0); opart first written after final tile
    float opart[4][192];          // barrier.
  };
  unsigned char maskbuf[256];
  float wm[4], wl[4];             // per-wave softmax state
  float w3buf[32];
  float b2buf[32];
  float consts[4];                // a1, a2, b3
};

__global__ __launch_bounds__(256, 4) void rich_attn_kernel(
    const float* __restrict__ query, const float* __restrict__ keys,
    const int*   __restrict__ keys_mask, const float* __restrict__ W1,
    const float* __restrict__ b1, const float* __restrict__ a1,
    const float* __restrict__ W2, const float* __restrict__ b2,
    const float* __restrict__ a2, const float* __restrict__ W3,
    const float* __restrict__ b3, float* __restrict__ out)
{
  __shared__ Smem sm;
  const int tid  = threadIdx.x;
  const int b    = blockIdx.x;
  const int wave = tid >> 6;
  const int lane = tid & 63;
  const int quad = (tid >> 4) & 3;
  const int n16  = tid & 15;

  // ---- phase A: preload q, mask, scalars, W2^T(bf16), W3 ----
  if (tid < 192) sm.qbuf[tid] = query[b*D_N + tid];
  sm.maskbuf[tid] = (tid < 200) ? (unsigned char)(keys_mask[b*S_N + tid] != 0) : 0;
  if (tid < 32)  sm.w3buf[tid] = W3[tid];
  else if (tid < 64) sm.b2buf[tid-32] = b2[tid-32];
  if (tid == 64) { sm.consts[0] = a1[0]; sm.consts[1] = a2[0]; sm.consts[2] = b3[0]; }
  for (int i = tid; i < 64*32; i += 256) {
    int hh = i >> 5, kk = i & 31;                 // W2[h][k2] row-major
    *((__bf16*)&sm.w2t[kk*144 + hh*2]) = (__bf16)W2[i];
  }
  __syncthreads();

  // ---- phase B: c_b partials; per-wave fb1 (M_b cols, registers); fw2 ----
  {
    int hh = tid & 63, pp = tid >> 6;
    float acc = 0.f;
    int d0 = pp*48;
    #pragma unroll 4
    for (int d = d0; d < d0+48; ++d)
      acc += sm.qbuf[d] * (W1[(192+d)*64 + hh] - W1[(576+d)*64 + hh]);
    sm.cpart[pp][hh] = acc;
  }
  bf16x8 fb1[6];                                  // B-frag: M_b[k=t*32+quad*8+j][n=h]
  {
    int h = (wave << 4) | n16;
    #pragma unroll
    for (int t = 0; t < 6; ++t) {
      #pragma unroll
      for (int j = 0; j < 8; ++j) {
        int d = t*32 + quad*8 + j;
        float v = W1[d*64 + h] + W1[(576+d)*64 + h] + sm.qbuf[d]*W1[(384+d)*64 + h];
        fb1[t][j] = (__bf16)v;
      }
      __builtin_amdgcn_sched_barrier(0);          // cap in-flight loads/t-group
    }
  }
  bf16x8 fw2[2][2];                               // B-frags for GEMM2, both n-tiles
  #pragma unroll
  for (int nt2 = 0; nt2 < 2; ++nt2)
    #pragma unroll
    for (int t = 0; t < 2; ++t)
      fw2[nt2][t] = *(const bf16x8*)&sm.w2t[(nt2*16 + n16)*144 + (t*32 + quad*8)*2];
  // PER-LANE (n16-indexed) -> must stay in VGPRs (R2 bug: these were rfl'd)
  const float w3v0 = sm.w3buf[n16],      w3v1 = sm.w3buf[16 + n16];
  const float bbv0 = sm.b2buf[n16],      bbv1 = sm.b2buf[16 + n16];
  // true scalars -> SGPRs
  const float a1v = rfl(sm.consts[0]), a2v = rfl(sm.consts[1]), b3v = rfl(sm.consts[2]);
  __syncthreads();
  if (tid < 64)
    sm.cbuf[tid] = b1[tid] + sm.cpart[0][tid] + sm.cpart[1][tid]
                 + sm.cpart[2][tid] + sm.cpart[3][tid];
  // cbuf first read after tile-0 staging barrier below.

  const float* kb = keys + (size_t)b * (S_N * D_N);
  float m_run = -1e30f, l_run = 0.f;
  f32x4 o = {0.f, 0.f, 0.f, 0.f};                 // lanes 0..47 own d = lane*4..+3 (per wave)

  for (int tile = 0; tile < 4; ++tile) {
    const int s0 = tile * 64;
    // ---- stage 64-row keys tile (f32 -> bf16 LDS), zero-fill past S ----
    // 3 chunks of 4 float4 to cap register liveness (R2: was 12 in flight).
    #pragma unroll
    for (int ch = 0; ch < 3; ++ch) {
      float4 v[4];
      #pragma unroll
      for (int u = 0; u < 4; ++u) {
        int f = tid + (ch*4 + u)*256;             // 0..3071
        int sg = s0 + f/48;
        v[u] = make_float4(0.f, 0.f, 0.f, 0.f);
        if (sg < 200) v[u] = ((const float4*)kb)[sg*48 + (f%48)];
      }
      #pragma unroll
      for (int u = 0; u < 4; ++u) {
        int f = tid + (ch*4 + u)*256;
        int row = f/48, c4 = f%48;
        bf16x4 bv;
        bv[0]=(__bf16)v[u].x; bv[1]=(__bf16)v[u].y;
        bv[2]=(__bf16)v[u].z; bv[3]=(__bf16)v[u].w;
        *(bf16x4*)&sm.kbuf[row*400 + c4*8] = bv;
      }
      __builtin_amdgcn_sched_barrier(0);
    }
    __syncthreads();

    // ---- GEMM1: h1_pre[64 x 64]; wave owns h-cols [16w,16w+16) ----
    f32x4 acc1[4];
    #pragma unroll
    for (int mt = 0; mt < 4; ++mt) acc1[mt] = (f32x4){0.f,0.f,0.f,0.f};
    #pragma unroll
    for (int mt = 0; mt < 4; ++mt)
      #pragma unroll
      for (int t = 0; t < 6; ++t) {
        bf16x8 fa = *(const bf16x8*)&sm.kbuf[(mt*16 + n16)*400 + (t*32 + quad*8)*2];
        acc1[mt] = __builtin_amdgcn_mfma_f32_16x16x32_bf16(fa, fb1[t], acc1[mt], 0, 0, 0);
      }
    {
      int h = (wave << 4) | n16;
      float cb = sm.cbuf[h];
      #pragma unroll
      for (int mt = 0; mt < 4; ++mt)
        #pragma unroll
        for (int r = 0; r < 4; ++r) {
          int m = mt*16 + quad*4 + r;             // C layout: row=quad*4+r, col=n16
          float v = acc1[mt][r] + cb;
          v = (v >= 0.f) ? v : a1v * v;
          *((__bf16*)&sm.h1buf[m*144 + h*2]) = (__bf16)v;
        }
    }
    __syncthreads();

    // ---- per-wave from here: rows 16*wave .. 16*wave+15 of this tile ----
    // GEMM2: h2_pre[16 x 32]
    bf16x8 fa2[2];
    #pragma unroll
    for (int t = 0; t < 2; ++t)
      fa2[t] = *(const bf16x8*)&sm.h1buf[(wave*16 + n16)*144 + (t*32 + quad*8)*2];
    f32x4 acc2[2];
    acc2[0] = (f32x4){0.f,0.f,0.f,0.f};
    acc2[1] = (f32x4){0.f,0.f,0.f,0.f};
    #pragma unroll
    for (int nt2 = 0; nt2 < 2; ++nt2)
      #pragma unroll
      for (int t = 0; t < 2; ++t)
        acc2[nt2] = __builtin_amdgcn_mfma_f32_16x16x32_bf16(fa2[t], fw2[nt2][t], acc2[nt2], 0, 0, 0);

    // layer 3 in-register: sc[r] for row (quad*4+r), butterfly-reduce over n16
    float sc[4];
    #pragma unroll
    for (int r = 0; r < 4; ++r) {
      float v0 = acc2[0][r] + bbv0; v0 = (v0 >= 0.f) ? v0 : a2v * v0;
      float v1 = acc2[1][r] + bbv1; v1 = (v1 >= 0.f) ? v1 : a2v * v1;
      sc[r] = v0 * w3v0 + v1 * w3v1;
    }
    #pragma unroll
    for (int off = 1; off < 16; off <<= 1)
      #pragma unroll
      for (int r = 0; r < 4; ++r) sc[r] += __shfl_xor(sc[r], off);

    // mask + per-wave online softmax (wave-local, no barrier)
    float p[4];
    float mloc = -1e30f;
    #pragma unroll
    for (int r = 0; r < 4; ++r) {
      int sg = s0 + wave*16 + quad*4 + r;
      sc[r] += b3v;
      bool valid = (sg < 200) && (sm.maskbuf[sg] != 0);
      sc[r] = valid ? sc[r] : -1e30f;
      mloc = fmaxf(mloc, sc[r]);
    }
    if (n16 == 0) {
      #pragma unroll
      for (int r = 0; r < 4; ++r) sm.scores[s0 + wave*16 + quad*4 + r] = sc[r];
    }
    mloc = fmaxf(mloc, __shfl_xor(mloc, 16));
    mloc = fmaxf(mloc, __shfl_xor(mloc, 32));
    float m_new = fmaxf(m_run, mloc);
    float fac = __expf(m_run - m_new);
    float psum = 0.f;
    #pragma unroll
    for (int r = 0; r < 4; ++r) {
      p[r] = (sc[r] > -1e29f) ? __expf(sc[r] - m_new) : 0.f;
      psum += p[r];
    }
    psum += __shfl_xor(psum, 16);
    psum += __shfl_xor(psum, 32);
    l_run = l_run * fac + psum;
    m_run = m_new;

    // o += p * keys over wave's 16 rows; p broadcast inline (short liveness)
    o[0] *= fac; o[1] *= fac; o[2] *= fac; o[3] *= fac;
    #pragma unroll
    for (int s2 = 0; s2 < 16; ++s2) {
      float pvs = __shfl(p[s2 & 3], (s2 >> 2) * 16);   // all lanes active
      if (lane < 48) {
        bf16x4 kv = *(const bf16x4*)&sm.kbuf[(wave*16 + s2)*400 + lane*8];
        o[0] += pvs * (float)kv[0];
        o[1] += pvs * (float)kv[1];
        o[2] += pvs * (float)kv[2];
        o[3] += pvs * (float)kv[3];
      }
    }
    __syncthreads();   // kbuf/h1buf reuse next tile
  }

  // ---- combine 4 per-wave states, finalize ----
  if (lane == 0) { sm.wm[wave] = m_run; sm.wl[wave] = l_run; }
  if (lane < 48) *(f32x4*)&sm.opart[wave][lane*4] = o;
  __syncthreads();
  float mg = fmaxf(fmaxf(sm.wm[0], sm.wm[1]), fmaxf(sm.wm[2], sm.wm[3]));
  float e0 = __expf(sm.wm[0] - mg), e1 = __expf(sm.wm[1] - mg);
  float e2 = __expf(sm.wm[2] - mg), e3 = __expf(sm.wm[3] - mg);
  float lg = sm.wl[0]*e0 + sm.wl[1]*e1 + sm.wl[2]*e2 + sm.wl[3]*e3;
  float invl = (lg > 0.f) ? 1.f / lg : 0.f;
  if (tid < 192) {
    float os = sm.opart[0][tid]*e0 + sm.opart[1][tid]*e1
             + sm.opart[2][tid]*e2 + sm.opart[3][tid]*e3;
    out[(size_t)b * D_N + tid] = os * invl;
  }
  if (tid < 200) {
    float wv = (lg > 0.f) ? __expf(sm.scores[tid] - mg) * invl : 0.f;
    out[(size_t)B_N * D_N + (size_t)b * S_N + tid] = wv;
  }
}

extern "C" void kernel_launch(void* const* d_in, const int* in_sizes, int n_in,
                              void* d_out, int out_size, void* d_ws, size_t ws_size,
                              hipStream_t stream) {
  const float* query     = (const float*)d_in[0];
  const float* keys      = (const float*)d_in[1];
  const int*   keys_mask = (const int*)  d_in[2];
  const float* W1        = (const float*)d_in[3];
  const float* b1        = (const float*)d_in[4];
  const float* a1        = (const float*)d_in[5];
  const float* W2        = (const float*)d_in[6];
  const float* b2        = (const float*)d_in[7];
  const float* a2        = (const float*)d_in[8];
  const float* W3        = (const float*)d_in[9];
  const float* b3        = (const float*)d_in[10];
  float* out = (float*)d_out;
  rich_attn_kernel<<<dim3(B_N), dim3(256), 0, stream>>>(
      query, keys, keys_mask, W1, b1, a1, W2, b2, a2, W3, b3, out);
}

// Round 4
// 521.984 us; speedup vs baseline: 1.0305x; 1.0274x over previous
//
#include <hip/hip_runtime.h>

// RichAttentionLayer: B=2048, S=200, D=192, H1=64, H2=32, IN=768.
// One block per batch b. Layer-1 decomposed:
//   x@W1 = k @ M_b + c_b,  M_b[d,h] = W1a[d,h] + W1d[d,h] + q[d]*W1c[d,h]
//   c_b[h] = b1[h] + sum_d q[d]*(W1b[d,h] - W1d[d,h])
// 64-row S-tiles. GEMM1 h-split across waves; GEMM2/layer3/softmax/o-accum
// fully per-wave -> 3 barriers per tile, no wave-serial sections.
//
// R1: LDS diet 46.9K -> 38.8K (unions) -> __launch_bounds__(256,4).
// R3: anti-spill scheduling; rfl on true scalars only. Result: VGPR=64,
//     WRITE_SIZE still 205 MB -> unified-file split is 64 arch / 64 acc
//     (fb1 24 + fw2 16 + acc1 16 + acc2 8 = 64 AGPR exactly); 64 arch regs
//     force ~100 scratch slots.
// R4: shrink acc demand so the split gives arch more room:
//  - GEMM1 single-mt accumulator (16 -> 4 AGPR) + per-mt sched_barrier
//    (caps fa ds_read in-flight at 6 instead of 24)
//  - fb1 build fenced every 4 j (12 W1 loads in flight)

#define B_N 2048
#define S_N 200
#define D_N 192

typedef __bf16 bf16x8 __attribute__((ext_vector_type(8)));
typedef __bf16 bf16x4 __attribute__((ext_vector_type(4)));
typedef float  f32x4  __attribute__((ext_vector_type(4)));

__device__ __forceinline__ float rfl(float x) {
  return __uint_as_float(__builtin_amdgcn_readfirstlane(__float_as_uint(x)));
}

struct __align__(16) Smem {
  unsigned char kbuf[64*400];     // bf16[64][200] (192 used), row stride 400 B
  union {                         // w2t consumed into regs before phase-B
    unsigned char h1buf[64*144];  // barrier; h1buf first written after it.
    unsigned char w2t[32*144];    // bf16 w2t[k2][h] = W2[h][k2]
  };
  union {                         // qbuf dead after phase-B barrier; scores
    float qbuf[192];              // first written tile 0 post-staging-barrier.
    float scores[256];
  };
  float cbuf[64];
  union {                         // cpart dead after cbuf computed (pre tile
    float cpart[4][64];           // 0); opart first written after final tile
    float opart[4][192];          // barrier.
  };
  unsigned char maskbuf[256];
  float wm[4], wl[4];             // per-wave softmax state
  float w3buf[32];
  float b2buf[32];
  float consts[4];                // a1, a2, b3
};

__global__ __launch_bounds__(256, 4) void rich_attn_kernel(
    const float* __restrict__ query, const float* __restrict__ keys,
    const int*   __restrict__ keys_mask, const float* __restrict__ W1,
    const float* __restrict__ b1, const float* __restrict__ a1,
    const float* __restrict__ W2, const float* __restrict__ b2,
    const float* __restrict__ a2, const float* __restrict__ W3,
    const float* __restrict__ b3, float* __restrict__ out)
{
  __shared__ Smem sm;
  const int tid  = threadIdx.x;
  const int b    = blockIdx.x;
  const int wave = tid >> 6;
  const int lane = tid & 63;
  const int quad = (tid >> 4) & 3;
  const int n16  = tid & 15;

  // ---- phase A: preload q, mask, scalars, W2^T(bf16), W3 ----
  if (tid < 192) sm.qbuf[tid] = query[b*D_N + tid];
  sm.maskbuf[tid] = (tid < 200) ? (unsigned char)(keys_mask[b*S_N + tid] != 0) : 0;
  if (tid < 32)  sm.w3buf[tid] = W3[tid];
  else if (tid < 64) sm.b2buf[tid-32] = b2[tid-32];
  if (tid == 64) { sm.consts[0] = a1[0]; sm.consts[1] = a2[0]; sm.consts[2] = b3[0]; }
  for (int i = tid; i < 64*32; i += 256) {
    int hh = i >> 5, kk = i & 31;                 // W2[h][k2] row-major
    *((__bf16*)&sm.w2t[kk*144 + hh*2]) = (__bf16)W2[i];
  }
  __syncthreads();

  // ---- phase B: c_b partials; per-wave fb1 (M_b cols, registers); fw2 ----
  {
    int hh = tid & 63, pp = tid >> 6;
    float acc = 0.f;
    int d0 = pp*48;
    #pragma unroll 4
    for (int d = d0; d < d0+48; ++d)
      acc += sm.qbuf[d] * (W1[(192+d)*64 + hh] - W1[(576+d)*64 + hh]);
    sm.cpart[pp][hh] = acc;
  }
  bf16x8 fb1[6];                                  // B-frag: M_b[k=t*32+quad*8+j][n=h]
  {
    int h = (wave << 4) | n16;
    #pragma unroll
    for (int t = 0; t < 6; ++t) {
      #pragma unroll
      for (int jh = 0; jh < 2; ++jh) {
        #pragma unroll
        for (int j2 = 0; j2 < 4; ++j2) {
          int j = jh*4 + j2;
          int d = t*32 + quad*8 + j;
          float v = W1[d*64 + h] + W1[(576+d)*64 + h] + sm.qbuf[d]*W1[(384+d)*64 + h];
          fb1[t][j] = (__bf16)v;
        }
        __builtin_amdgcn_sched_barrier(0);        // cap in-flight W1 loads at 12
      }
    }
  }
  bf16x8 fw2[2][2];                               // B-frags for GEMM2, both n-tiles
  #pragma unroll
  for (int nt2 = 0; nt2 < 2; ++nt2)
    #pragma unroll
    for (int t = 0; t < 2; ++t)
      fw2[nt2][t] = *(const bf16x8*)&sm.w2t[(nt2*16 + n16)*144 + (t*32 + quad*8)*2];
  // PER-LANE (n16-indexed) -> must stay in VGPRs
  const float w3v0 = sm.w3buf[n16],      w3v1 = sm.w3buf[16 + n16];
  const float bbv0 = sm.b2buf[n16],      bbv1 = sm.b2buf[16 + n16];
  // true scalars -> SGPRs
  const float a1v = rfl(sm.consts[0]), a2v = rfl(sm.consts[1]), b3v = rfl(sm.consts[2]);
  __syncthreads();
  if (tid < 64)
    sm.cbuf[tid] = b1[tid] + sm.cpart[0][tid] + sm.cpart[1][tid]
                 + sm.cpart[2][tid] + sm.cpart[3][tid];
  // cbuf first read after tile-0 staging barrier below.

  const float* kb = keys + (size_t)b * (S_N * D_N);
  float m_run = -1e30f, l_run = 0.f;
  f32x4 o = {0.f, 0.f, 0.f, 0.f};                 // lanes 0..47 own d = lane*4..+3 (per wave)

  for (int tile = 0; tile < 4; ++tile) {
    const int s0 = tile * 64;
    // ---- stage 64-row keys tile (f32 -> bf16 LDS), zero-fill past S ----
    // 3 chunks of 4 float4 to cap register liveness.
    #pragma unroll
    for (int ch = 0; ch < 3; ++ch) {
      float4 v[4];
      #pragma unroll
      for (int u = 0; u < 4; ++u) {
        int f = tid + (ch*4 + u)*256;             // 0..3071
        int sg = s0 + f/48;
        v[u] = make_float4(0.f, 0.f, 0.f, 0.f);
        if (sg < 200) v[u] = ((const float4*)kb)[sg*48 + (f%48)];
      }
      #pragma unroll
      for (int u = 0; u < 4; ++u) {
        int f = tid + (ch*4 + u)*256;
        int row = f/48, c4 = f%48;
        bf16x4 bv;
        bv[0]=(__bf16)v[u].x; bv[1]=(__bf16)v[u].y;
        bv[2]=(__bf16)v[u].z; bv[3]=(__bf16)v[u].w;
        *(bf16x4*)&sm.kbuf[row*400 + c4*8] = bv;
      }
      __builtin_amdgcn_sched_barrier(0);
    }
    __syncthreads();

    // ---- GEMM1: h1_pre[64 x 64]; wave owns h-cols [16w,16w+16) ----
    // R4: one mt-tile at a time (4 AGPR acc, <=6 fa ds_reads in flight).
    {
      int h = (wave << 4) | n16;
      float cb = sm.cbuf[h];
      #pragma unroll
      for (int mt = 0; mt < 4; ++mt) {
        f32x4 acc1 = (f32x4){0.f,0.f,0.f,0.f};
        #pragma unroll
        for (int t = 0; t < 6; ++t) {
          bf16x8 fa = *(const bf16x8*)&sm.kbuf[(mt*16 + n16)*400 + (t*32 + quad*8)*2];
          acc1 = __builtin_amdgcn_mfma_f32_16x16x32_bf16(fa, fb1[t], acc1, 0, 0, 0);
        }
        #pragma unroll
        for (int r = 0; r < 4; ++r) {
          int m = mt*16 + quad*4 + r;             // C layout: row=quad*4+r, col=n16
          float v = acc1[r] + cb;
          v = (v >= 0.f) ? v : a1v * v;
          *((__bf16*)&sm.h1buf[m*144 + h*2]) = (__bf16)v;
        }
        __builtin_amdgcn_sched_barrier(0);        // fence: don't hoist next mt's reads
      }
    }
    __syncthreads();

    // ---- per-wave from here: rows 16*wave .. 16*wave+15 of this tile ----
    // GEMM2: h2_pre[16 x 32]
    bf16x8 fa2[2];
    #pragma unroll
    for (int t = 0; t < 2; ++t)
      fa2[t] = *(const bf16x8*)&sm.h1buf[(wave*16 + n16)*144 + (t*32 + quad*8)*2];
    f32x4 acc2[2];
    acc2[0] = (f32x4){0.f,0.f,0.f,0.f};
    acc2[1] = (f32x4){0.f,0.f,0.f,0.f};
    #pragma unroll
    for (int nt2 = 0; nt2 < 2; ++nt2)
      #pragma unroll
      for (int t = 0; t < 2; ++t)
        acc2[nt2] = __builtin_amdgcn_mfma_f32_16x16x32_bf16(fa2[t], fw2[nt2][t], acc2[nt2], 0, 0, 0);

    // layer 3 in-register: sc[r] for row (quad*4+r), butterfly-reduce over n16
    float sc[4];
    #pragma unroll
    for (int r = 0; r < 4; ++r) {
      float v0 = acc2[0][r] + bbv0; v0 = (v0 >= 0.f) ? v0 : a2v * v0;
      float v1 = acc2[1][r] + bbv1; v1 = (v1 >= 0.f) ? v1 : a2v * v1;
      sc[r] = v0 * w3v0 + v1 * w3v1;
    }
    #pragma unroll
    for (int off = 1; off < 16; off <<= 1)
      #pragma unroll
      for (int r = 0; r < 4; ++r) sc[r] += __shfl_xor(sc[r], off);

    // mask + per-wave online softmax (wave-local, no barrier)
    float p[4];
    float mloc = -1e30f;
    #pragma unroll
    for (int r = 0; r < 4; ++r) {
      int sg = s0 + wave*16 + quad*4 + r;
      sc[r] += b3v;
      bool valid = (sg < 200) && (sm.maskbuf[sg] != 0);
      sc[r] = valid ? sc[r] : -1e30f;
      mloc = fmaxf(mloc, sc[r]);
    }
    if (n16 == 0) {
      #pragma unroll
      for (int r = 0; r < 4; ++r) sm.scores[s0 + wave*16 + quad*4 + r] = sc[r];
    }
    mloc = fmaxf(mloc, __shfl_xor(mloc, 16));
    mloc = fmaxf(mloc, __shfl_xor(mloc, 32));
    float m_new = fmaxf(m_run, mloc);
    float fac = __expf(m_run - m_new);
    float psum = 0.f;
    #pragma unroll
    for (int r = 0; r < 4; ++r) {
      p[r] = (sc[r] > -1e29f) ? __expf(sc[r] - m_new) : 0.f;
      psum += p[r];
    }
    psum += __shfl_xor(psum, 16);
    psum += __shfl_xor(psum, 32);
    l_run = l_run * fac + psum;
    m_run = m_new;

    // o += p * keys over wave's 16 rows; p broadcast inline (short liveness)
    o[0] *= fac; o[1] *= fac; o[2] *= fac; o[3] *= fac;
    #pragma unroll
    for (int s2 = 0; s2 < 16; ++s2) {
      float pvs = __shfl(p[s2 & 3], (s2 >> 2) * 16);   // all lanes active
      if (lane < 48) {
        bf16x4 kv = *(const bf16x4*)&sm.kbuf[(wave*16 + s2)*400 + lane*8];
        o[0] += pvs * (float)kv[0];
        o[1] += pvs * (float)kv[1];
        o[2] += pvs * (float)kv[2];
        o[3] += pvs * (float)kv[3];
      }
    }
    __syncthreads();   // kbuf/h1buf reuse next tile
  }

  // ---- combine 4 per-wave states, finalize ----
  if (lane == 0) { sm.wm[wave] = m_run; sm.wl[wave] = l_run; }
  if (lane < 48) *(f32x4*)&sm.opart[wave][lane*4] = o;
  __syncthreads();
  float mg = fmaxf(fmaxf(sm.wm[0], sm.wm[1]), fmaxf(sm.wm[2], sm.wm[3]));
  float e0 = __expf(sm.wm[0] - mg), e1 = __expf(sm.wm[1] - mg);
  float e2 = __expf(sm.wm[2] - mg), e3 = __expf(sm.wm[3] - mg);
  float lg = sm.wl[0]*e0 + sm.wl[1]*e1 + sm.wl[2]*e2 + sm.wl[3]*e3;
  float invl = (lg > 0.f) ? 1.f / lg : 0.f;
  if (tid < 192) {
    float os = sm.opart[0][tid]*e0 + sm.opart[1][tid]*e1
             + sm.opart[2][tid]*e2 + sm.opart[3][tid]*e3;
    out[(size_t)b * D_N + tid] = os * invl;
  }
  if (tid < 200) {
    float wv = (lg > 0.f) ? __expf(sm.scores[tid] - mg) * invl : 0.f;
    out[(size_t)B_N * D_N + (size_t)b * S_N + tid] = wv;
  }
}

extern "C" void kernel_launch(void* const* d_in, const int* in_sizes, int n_in,
                              void* d_out, int out_size, void* d_ws, size_t ws_size,
                              hipStream_t stream) {
  const float* query     = (const float*)d_in[0];
  const float* keys      = (const float*)d_in[1];
  const int*   keys_mask = (const int*)  d_in[2];
  const float* W1        = (const float*)d_in[3];
  const float* b1        = (const float*)d_in[4];
  const float* a1        = (const float*)d_in[5];
  const float* W2        = (const float*)d_in[6];
  const float* b2        = (const float*)d_in[7];
  const float* a2        = (const float*)d_in[8];
  const float* W3        = (const float*)d_in[9];
  const float* b3        = (const float*)d_in[10];
  float* out = (float*)d_out;
  rich_attn_kernel<<<dim3(B_N), dim3(256), 0, stream>>>(
      query, keys, keys_mask, W1, b1, a1, W2, b2, a2, W3, b3, out);
}